// Round 1
// baseline (575.242 us; speedup 1.0000x reference)
//
#include <hip/hip_runtime.h>

#define NPIX 1024
#define CIN  256
#define EPSV 1e-5f

typedef __attribute__((ext_vector_type(8))) short bf16x8;
typedef __attribute__((ext_vector_type(4))) float f32x4;

__device__ __forceinline__ short f2bf(float f) {
  unsigned u = __float_as_uint(f);
  unsigned r = (u + 0x7FFFu + ((u >> 16) & 1u)) >> 16;
  return (short)r;
}

// ---------------- K0: weights fp32 -> bf16 (rows stay k-contiguous) ----------
__global__ __launch_bounds__(256) void wcvt(
    const float* __restrict__ wq, const float* __restrict__ wih,
    const float* __restrict__ whh, const float* __restrict__ w1,
    const float* __restrict__ w2,
    short* __restrict__ wq_b, short* __restrict__ wih_b, short* __restrict__ whh_b,
    short* __restrict__ w1_b, short* __restrict__ w2_b) {
  int id = blockIdx.x * 256 + threadIdx.x;
  if      (id <  65536) wq_b [id         ] = f2bf(wq [id         ]);
  else if (id < 262144) wih_b[id -  65536] = f2bf(wih[id -  65536]);
  else if (id < 458752) whh_b[id - 262144] = f2bf(whh[id - 262144]);
  else if (id < 524288) w1_b [id - 458752] = f2bf(w1 [id - 458752]);
  else if (id < 589824) w2_b [id - 524288] = f2bf(w2 [id - 524288]);
}

// ---------------- K1: per-pixel LayerNorm stats over C ----------------------
__global__ __launch_bounds__(256) void ln_stats(
    const float* __restrict__ x, float* __restrict__ mu, float* __restrict__ rstd) {
  int p = blockIdx.x * 256 + threadIdx.x;   // 0..65535
  int b = p >> 10, n = p & 1023;
  const float* xp = x + (size_t)b * CIN * NPIX + n;
  float s = 0.f, sq = 0.f;
  #pragma unroll 8
  for (int c = 0; c < CIN; c++) { float v = xp[(size_t)c * NPIX]; s += v; sq += v * v; }
  float m = s * (1.f / 256.f);
  float var = sq * (1.f / 256.f) - m * m;
  mu[p] = m;
  rstd[p] = rsqrtf(var + EPSV);
}

// ---------------- K2: fused LN + [k|v] projection (bf16 MFMA) ---------------
// out dims 0..255 -> k[b][pix][d] (bf16); dims 256..511 -> vT[b][d][pix] (bf16)
#define BKP 72
__global__ __launch_bounds__(256) void kv_gemm(
    const float* __restrict__ x, const float* __restrict__ mu,
    const float* __restrict__ rstd,
    const float* __restrict__ gam, const float* __restrict__ bet,
    const float* __restrict__ wk, const float* __restrict__ wv,
    short* __restrict__ kout, short* __restrict__ vTout) {
  __shared__ short As[128 * BKP];   // [m=pixel][k=c]
  __shared__ short Bs[128 * BKP];   // [n=dim ][k=c]
  __shared__ float mus[128], rss[128];
  int t = threadIdx.x;
  int bid = blockIdx.x;
  int nt = bid & 3, mt = bid >> 2;
  int pbase = mt << 7;
  int b = pbase >> 10;
  int n0 = pbase & 1023;
  if (t < 128) { mus[t] = mu[pbase + t]; rss[t] = rstd[pbase + t]; }
  f32x4 acc[4][4];
  for (int i = 0; i < 4; i++)
    for (int j = 0; j < 4; j++) acc[i][j] = 0.f;
  const float* wbase = (nt < 2) ? wk : wv;
  int drow0 = (nt & 1) << 7;
  int mloc = t & 127, grp = t >> 7;
  const float* xb = x + (size_t)b * CIN * NPIX + n0 + mloc;
  int w = t >> 6, lane = t & 63, quad = lane >> 4, lid = lane & 15;
  int wm = w & 1, wn = w >> 1;
  __syncthreads();
  float mm = mus[mloc], rr = rss[mloc];
  for (int kt = 0; kt < 4; kt++) {
    int c0 = kt << 6;
    // stage A (transpose: global [c][pix] -> LDS [pix][c]), LN applied
    #pragma unroll
    for (int p = 0; p < 8; p++) {
      int kl = (p << 3) + (grp << 2);
      int c = c0 + kl;
      float v0 = xb[(size_t)(c + 0) * NPIX];
      float v1 = xb[(size_t)(c + 1) * NPIX];
      float v2 = xb[(size_t)(c + 2) * NPIX];
      float v3 = xb[(size_t)(c + 3) * NPIX];
      short4 hv;
      hv.x = f2bf((v0 - mm) * rr * gam[c + 0] + bet[c + 0]);
      hv.y = f2bf((v1 - mm) * rr * gam[c + 1] + bet[c + 1]);
      hv.z = f2bf((v2 - mm) * rr * gam[c + 2] + bet[c + 2]);
      hv.w = f2bf((v3 - mm) * rr * gam[c + 3] + bet[c + 3]);
      *(short4*)&As[mloc * BKP + kl] = hv;
    }
    // stage B (weights, already k-contiguous)
    #pragma unroll
    for (int p = 0; p < 8; p++) {
      int r = (p << 4) + (t >> 4);
      int cc = (t & 15) << 2;
      float4 w4 = *(const float4*)(wbase + (size_t)(drow0 + r) * 256 + c0 + cc);
      short4 hv;
      hv.x = f2bf(w4.x); hv.y = f2bf(w4.y); hv.z = f2bf(w4.z); hv.w = f2bf(w4.w);
      *(short4*)&Bs[r * BKP + cc] = hv;
    }
    __syncthreads();
    #pragma unroll
    for (int kk = 0; kk < 64; kk += 32) {
      bf16x8 af[4], bfr[4];
      #pragma unroll
      for (int i = 0; i < 4; i++)
        af[i] = *(const bf16x8*)&As[(wm * 64 + i * 16 + lid) * BKP + kk + quad * 8];
      #pragma unroll
      for (int j = 0; j < 4; j++)
        bfr[j] = *(const bf16x8*)&Bs[(wn * 64 + j * 16 + lid) * BKP + kk + quad * 8];
      #pragma unroll
      for (int i = 0; i < 4; i++)
        #pragma unroll
        for (int j = 0; j < 4; j++)
          acc[i][j] = __builtin_amdgcn_mfma_f32_16x16x32_bf16(af[i], bfr[j], acc[i][j], 0, 0, 0);
    }
    __syncthreads();
  }
  // epilogue: D row = quad*4+reg (pixel), col = lid (dim)
  #pragma unroll
  for (int i = 0; i < 4; i++) {
    int pl = n0 + wm * 64 + i * 16 + quad * 4;   // local pixel (row base)
    #pragma unroll
    for (int j = 0; j < 4; j++) {
      int dim = (nt << 7) + wn * 64 + j * 16 + lid;
      if (nt < 2) {
        #pragma unroll
        for (int r = 0; r < 4; r++)
          kout[((size_t)((b << 10) + pl + r)) * 256 + dim] = f2bf(acc[i][j][r]);
      } else {
        short4 hv;
        hv.x = f2bf(acc[i][j][0]); hv.y = f2bf(acc[i][j][1]);
        hv.z = f2bf(acc[i][j][2]); hv.w = f2bf(acc[i][j][3]);
        *(short4*)(vTout + (size_t)b * 262144 + (size_t)(dim - 256) * 1024 + pl) = hv;
      }
    }
  }
}

// ---------------- K3: fused 3-iteration slot attention (block per b) --------
#define SP 264
#define AP 1032
__global__ __launch_bounds__(1024) void slot_iter(
    const short* __restrict__ kbuf, const short* __restrict__ vT,
    const float* __restrict__ slots_mu,
    const float* __restrict__ lsg, const float* __restrict__ lsb,
    const short* __restrict__ wq_b,
    const short* __restrict__ wih_b, const short* __restrict__ whh_b,
    const float* __restrict__ bih, const float* __restrict__ bhh,
    const float* __restrict__ lmg, const float* __restrict__ lmb,
    const short* __restrict__ w1_b, const float* __restrict__ b1,
    const short* __restrict__ w2_b, const float* __restrict__ b2,
    float* __restrict__ out) {
  __shared__ float sl[8][256];
  __shared__ float mus[8], rss[8];
  __shared__ short slb[8 * SP], slnb[8 * SP], qsb[8 * SP], updb[8 * SP],
                   lnmb[8 * SP], hmb[8 * SP];
  __shared__ short attT[8 * AP];
  int b = blockIdx.x, t = threadIdx.x;
  int wave = t >> 6, lane = t & 63, quad = lane >> 4, lid = lane & 15;
  int d = (wave << 4) + lid;            // n-column for 256-wide MFMA stages
  int arow = (lid & 7) * SP;            // A-operand row (8 slots duplicated to 16)
  int kof0 = quad << 3;
  for (int idx = t; idx < 2048; idx += 1024) {
    float v = slots_mu[idx];
    sl[idx >> 8][idx & 255] = v;
    slb[(idx >> 8) * SP + (idx & 255)] = f2bf(v);
  }
  __syncthreads();
  float* out_attn = out + 131072;
  for (int iter = 0; iter < 3; iter++) {
    // ---- (1) LN(slots) -> slnb (bf16)
    if (wave < 8) {
      float s0 = 0.f, s1 = 0.f;
      #pragma unroll
      for (int j = 0; j < 4; j++) { float v = sl[wave][lane + (j << 6)]; s0 += v; s1 += v * v; }
      #pragma unroll
      for (int m = 1; m < 64; m <<= 1) { s0 += __shfl_xor(s0, m); s1 += __shfl_xor(s1, m); }
      if (lane == 0) {
        float mn = s0 * (1.f / 256.f);
        float var = s1 * (1.f / 256.f) - mn * mn;
        mus[wave] = mn; rss[wave] = rsqrtf(var + EPSV);
      }
    }
    __syncthreads();
    for (int idx = t; idx < 2048; idx += 1024) {
      int s = idx >> 8, c = idx & 255;
      slnb[s * SP + c] = f2bf((sl[s][c] - mus[s]) * rss[s] * lsg[c] + lsb[c]);
    }
    __syncthreads();
    // ---- (2) q = LN(slots) @ wq^T -> qsb (bf16)
    {
      f32x4 qa = 0.f;
      #pragma unroll
      for (int ks = 0; ks < 8; ks++) {
        bf16x8 a = *(const bf16x8*)&slnb[arow + (ks << 5) + kof0];
        bf16x8 bb = *(const bf16x8*)(wq_b + (size_t)d * 256 + (ks << 5) + kof0);
        qa = __builtin_amdgcn_mfma_f32_16x16x32_bf16(a, bb, qa, 0, 0, 0);
      }
      #pragma unroll
      for (int r = 0; r < 4; r++) {
        int s = (quad << 2) + r;
        if (s < 8) qsb[s * SP + d] = f2bf(qa[r]);
      }
    }
    __syncthreads();
    // ---- (3) logits = k @ q^T, softmax over slots -> attT (bf16), out_attn
    for (int mt2 = wave; mt2 < 64; mt2 += 16) {
      int p0 = mt2 << 4;
      f32x4 la = 0.f;
      const short* kb = kbuf + (size_t)((b << 10) + p0 + lid) * 256;
      #pragma unroll
      for (int ks = 0; ks < 8; ks++) {
        bf16x8 a = *(const bf16x8*)(kb + (ks << 5) + kof0);
        bf16x8 bb = *(const bf16x8*)&qsb[arow + (ks << 5) + kof0];
        la = __builtin_amdgcn_mfma_f32_16x16x32_bf16(a, bb, la, 0, 0, 0);
      }
      #pragma unroll
      for (int r = 0; r < 4; r++) {
        float lg = la[r] * 0.0625f;
        float mx = lg;
        #pragma unroll
        for (int m = 1; m < 16; m <<= 1) mx = fmaxf(mx, __shfl_xor(mx, m));
        float e = __expf(lg - mx);
        float sm = e;
        #pragma unroll
        for (int m = 1; m < 16; m <<= 1) sm += __shfl_xor(sm, m);
        float at = (e + e) / sm;        // cols 8..15 duplicate cols 0..7 -> sum is 2x
        if (lid < 8) {
          int p = p0 + (quad << 2) + r;
          attT[lid * AP + p] = f2bf(at);
          if (iter == 2) out_attn[((size_t)b << 13) + (p << 3) + lid] = at;
        }
      }
    }
    __syncthreads();
    // ---- (4) updates = attn^T @ v -> updb (bf16)
    {
      f32x4 ua = 0.f;
      const short* vb = vT + (size_t)b * 262144 + (size_t)d * 1024;
      #pragma unroll 8
      for (int ks = 0; ks < 32; ks++) {
        bf16x8 a = *(const bf16x8*)&attT[(lid & 7) * AP + (ks << 5) + kof0];
        bf16x8 bb = *(const bf16x8*)(vb + (ks << 5) + kof0);
        ua = __builtin_amdgcn_mfma_f32_16x16x32_bf16(a, bb, ua, 0, 0, 0);
      }
      #pragma unroll
      for (int r = 0; r < 4; r++) {
        int s = (quad << 2) + r;
        if (s < 8) updb[s * SP + d] = f2bf(ua[r]);
      }
    }
    __syncthreads();
    // ---- (5) GRU gates (gi = upd@wih^T, gh = slots@whh^T) + cell update
    {
      f32x4 gi[3], gh[3];
      #pragma unroll
      for (int g = 0; g < 3; g++) { gi[g] = 0.f; gh[g] = 0.f; }
      #pragma unroll
      for (int ks = 0; ks < 8; ks++) {
        bf16x8 au = *(const bf16x8*)&updb[arow + (ks << 5) + kof0];
        bf16x8 as = *(const bf16x8*)&slb[arow + (ks << 5) + kof0];
        #pragma unroll
        for (int g = 0; g < 3; g++) {
          bf16x8 bi = *(const bf16x8*)(wih_b + (size_t)((g << 8) + d) * 256 + (ks << 5) + kof0);
          bf16x8 bh = *(const bf16x8*)(whh_b + (size_t)((g << 8) + d) * 256 + (ks << 5) + kof0);
          gi[g] = __builtin_amdgcn_mfma_f32_16x16x32_bf16(au, bi, gi[g], 0, 0, 0);
          gh[g] = __builtin_amdgcn_mfma_f32_16x16x32_bf16(as, bh, gh[g], 0, 0, 0);
        }
      }
      float bi0 = bih[d], bi1 = bih[256 + d], bi2 = bih[512 + d];
      float bh0 = bhh[d], bh1 = bhh[256 + d], bh2 = bhh[512 + d];
      float hnew[4];
      #pragma unroll
      for (int r = 0; r < 4; r++) {
        int s = (quad << 2) + r;
        float rg = 1.f / (1.f + __expf(-(gi[0][r] + bi0 + gh[0][r] + bh0)));
        float zg = 1.f / (1.f + __expf(-(gi[1][r] + bi1 + gh[1][r] + bh1)));
        float ng = tanhf(gi[2][r] + bi2 + rg * (gh[2][r] + bh2));
        float hold = (s < 8) ? sl[s][d] : 0.f;
        hnew[r] = (1.f - zg) * ng + zg * hold;
      }
      #pragma unroll
      for (int r = 0; r < 4; r++) {
        int s = (quad << 2) + r;
        if (s < 8) sl[s][d] = hnew[r];      // (s,d) owner-exclusive, no race
      }
    }
    __syncthreads();
    // ---- (6) LN_m(slots) -> lnmb (bf16)
    if (wave < 8) {
      float s0 = 0.f, s1 = 0.f;
      #pragma unroll
      for (int j = 0; j < 4; j++) { float v = sl[wave][lane + (j << 6)]; s0 += v; s1 += v * v; }
      #pragma unroll
      for (int m = 1; m < 64; m <<= 1) { s0 += __shfl_xor(s0, m); s1 += __shfl_xor(s1, m); }
      if (lane == 0) {
        float mn = s0 * (1.f / 256.f);
        float var = s1 * (1.f / 256.f) - mn * mn;
        mus[wave] = mn; rss[wave] = rsqrtf(var + EPSV);
      }
    }
    __syncthreads();
    for (int idx = t; idx < 2048; idx += 1024) {
      int s = idx >> 8, c = idx & 255;
      lnmb[s * SP + c] = f2bf((sl[s][c] - mus[s]) * rss[s] * lmg[c] + lmb[c]);
    }
    __syncthreads();
    // ---- (7) hmid = relu(lnm @ w1^T + b1) -> hmb (bf16)
    {
      f32x4 ha = 0.f;
      #pragma unroll
      for (int ks = 0; ks < 8; ks++) {
        bf16x8 a = *(const bf16x8*)&lnmb[arow + (ks << 5) + kof0];
        bf16x8 bb = *(const bf16x8*)(w1_b + (size_t)d * 256 + (ks << 5) + kof0);
        ha = __builtin_amdgcn_mfma_f32_16x16x32_bf16(a, bb, ha, 0, 0, 0);
      }
      float bb1 = b1[d];
      #pragma unroll
      for (int r = 0; r < 4; r++) {
        int s = (quad << 2) + r;
        if (s < 8) hmb[s * SP + d] = f2bf(fmaxf(ha[r] + bb1, 0.f));
      }
    }
    __syncthreads();
    // ---- (8) slots += hmid @ w2^T + b2
    {
      f32x4 oa = 0.f;
      #pragma unroll
      for (int ks = 0; ks < 8; ks++) {
        bf16x8 a = *(const bf16x8*)&hmb[arow + (ks << 5) + kof0];
        bf16x8 bb = *(const bf16x8*)(w2_b + (size_t)d * 256 + (ks << 5) + kof0);
        oa = __builtin_amdgcn_mfma_f32_16x16x32_bf16(a, bb, oa, 0, 0, 0);
      }
      float bb2 = b2[d];
      #pragma unroll
      for (int r = 0; r < 4; r++) {
        int s = (quad << 2) + r;
        if (s < 8) {
          float o = sl[s][d] + oa[r] + bb2;
          sl[s][d] = o;
          slb[s * SP + d] = f2bf(o);
        }
      }
    }
    __syncthreads();
  }
  for (int idx = t; idx < 2048; idx += 1024)
    out[((size_t)b << 11) + idx] = sl[idx >> 8][idx & 255];
}

extern "C" void kernel_launch(void* const* d_in, const int* in_sizes, int n_in,
                              void* d_out, int out_size, void* d_ws, size_t ws_size,
                              hipStream_t stream) {
  const float* x        = (const float*)d_in[0];
  const float* slots_mu = (const float*)d_in[1];
  const float* ln_in_g  = (const float*)d_in[2];
  const float* ln_in_b  = (const float*)d_in[3];
  const float* wk       = (const float*)d_in[4];
  const float* wv       = (const float*)d_in[5];
  const float* ln_s_g   = (const float*)d_in[6];
  const float* ln_s_b   = (const float*)d_in[7];
  const float* wq       = (const float*)d_in[8];
  const float* wih      = (const float*)d_in[9];
  const float* whh      = (const float*)d_in[10];
  const float* bih      = (const float*)d_in[11];
  const float* bhh      = (const float*)d_in[12];
  const float* lmg      = (const float*)d_in[13];
  const float* lmb      = (const float*)d_in[14];
  const float* w1       = (const float*)d_in[15];
  const float* b1       = (const float*)d_in[16];
  const float* w2       = (const float*)d_in[17];
  const float* b2       = (const float*)d_in[18];
  float* out = (float*)d_out;

  char* ws = (char*)d_ws;
  short* kbuf  = (short*)(ws);                  // 64*1024*256 bf16 = 33,554,432 B
  short* vT    = (short*)(ws + 33554432);       // 33,554,432 B
  float* mu    = (float*)(ws + 67108864);       // 262,144 B
  float* rstd  = (float*)(ws + 67371008);       // 262,144 B
  short* wq_b  = (short*)(ws + 67633152);       // 131,072 B
  short* wih_b = (short*)(ws + 67764224);       // 393,216 B
  short* whh_b = (short*)(ws + 68157440);       // 393,216 B
  short* w1_b  = (short*)(ws + 68550656);       // 131,072 B
  short* w2_b  = (short*)(ws + 68681728);       // 131,072 B (end 68,812,800)

  wcvt<<<2304, 256, 0, stream>>>(wq, wih, whh, w1, w2, wq_b, wih_b, whh_b, w1_b, w2_b);
  ln_stats<<<256, 256, 0, stream>>>(x, mu, rstd);
  kv_gemm<<<2048, 256, 0, stream>>>(x, mu, rstd, ln_in_g, ln_in_b, wk, wv, kbuf, vT);
  slot_iter<<<64, 1024, 0, stream>>>(kbuf, vT, slots_mu, ln_s_g, ln_s_b, wq_b,
                                     wih_b, whh_b, bih, bhh, lmg, lmb,
                                     w1_b, b1, w2_b, b2, out);
}

// Round 2
// 447.252 us; speedup vs baseline: 1.2862x; 1.2862x over previous
//
#include <hip/hip_runtime.h>

#define NPIX 1024
#define CIN  256
#define EPSV 1e-5f
#define SP 264
#define AP 136

typedef __attribute__((ext_vector_type(8))) short bf16x8;
typedef __attribute__((ext_vector_type(4))) float f32x4;

__device__ __forceinline__ short f2bf(float f) {
  unsigned u = __float_as_uint(f);
  unsigned r = (u + 0x7FFFu + ((u >> 16) & 1u)) >> 16;
  return (short)r;
}

// ---------------- K0: weights fp32 -> bf16 (rows stay k-contiguous) ----------
__global__ __launch_bounds__(256) void wcvt(
    const float* __restrict__ wq, const float* __restrict__ wih,
    const float* __restrict__ whh, const float* __restrict__ w1,
    const float* __restrict__ w2,
    short* __restrict__ wq_b, short* __restrict__ wih_b, short* __restrict__ whh_b,
    short* __restrict__ w1_b, short* __restrict__ w2_b) {
  int id = blockIdx.x * 256 + threadIdx.x;
  if      (id <  65536) wq_b [id         ] = f2bf(wq [id         ]);
  else if (id < 262144) wih_b[id -  65536] = f2bf(wih[id -  65536]);
  else if (id < 458752) whh_b[id - 262144] = f2bf(whh[id - 262144]);
  else if (id < 524288) w1_b [id - 458752] = f2bf(w1 [id - 458752]);
  else if (id < 589824) w2_b [id - 524288] = f2bf(w2 [id - 524288]);
}

// ---------------- K1: per-pixel LayerNorm stats over C ----------------------
__global__ __launch_bounds__(256) void ln_stats(
    const float* __restrict__ x, float* __restrict__ mu, float* __restrict__ rstd) {
  int p = blockIdx.x * 256 + threadIdx.x;   // 0..65535
  int b = p >> 10, n = p & 1023;
  const float* xp = x + (size_t)b * CIN * NPIX + n;
  float s = 0.f, sq = 0.f;
  #pragma unroll 8
  for (int c = 0; c < CIN; c++) { float v = xp[(size_t)c * NPIX]; s += v; sq += v * v; }
  float m = s * (1.f / 256.f);
  float var = sq * (1.f / 256.f) - m * m;
  mu[p] = m;
  rstd[p] = rsqrtf(var + EPSV);
}

// ---------------- K2: fused LN + [k|v] projection (bf16 MFMA) ---------------
#define BKP 72
__global__ __launch_bounds__(256) void kv_gemm(
    const float* __restrict__ x, const float* __restrict__ mu,
    const float* __restrict__ rstd,
    const float* __restrict__ gam, const float* __restrict__ bet,
    const float* __restrict__ wk, const float* __restrict__ wv,
    short* __restrict__ kout, short* __restrict__ vTout) {
  __shared__ short As[128 * BKP];   // [m=pixel][k=c]
  __shared__ short Bs[128 * BKP];   // [n=dim ][k=c]
  __shared__ float mus[128], rss[128];
  int t = threadIdx.x;
  int bid = blockIdx.x;
  int nt = bid & 3, mt = bid >> 2;
  int pbase = mt << 7;
  int b = pbase >> 10;
  int n0 = pbase & 1023;
  if (t < 128) { mus[t] = mu[pbase + t]; rss[t] = rstd[pbase + t]; }
  f32x4 acc[4][4];
  for (int i = 0; i < 4; i++)
    for (int j = 0; j < 4; j++) acc[i][j] = 0.f;
  const float* wbase = (nt < 2) ? wk : wv;
  int drow0 = (nt & 1) << 7;
  int mloc = t & 127, grp = t >> 7;
  const float* xb = x + (size_t)b * CIN * NPIX + n0 + mloc;
  int w = t >> 6, lane = t & 63, quad = lane >> 4, lid = lane & 15;
  int wm = w & 1, wn = w >> 1;
  __syncthreads();
  float mm = mus[mloc], rr = rss[mloc];
  for (int kt = 0; kt < 4; kt++) {
    int c0 = kt << 6;
    #pragma unroll
    for (int p = 0; p < 8; p++) {
      int kl = (p << 3) + (grp << 2);
      int c = c0 + kl;
      float v0 = xb[(size_t)(c + 0) * NPIX];
      float v1 = xb[(size_t)(c + 1) * NPIX];
      float v2 = xb[(size_t)(c + 2) * NPIX];
      float v3 = xb[(size_t)(c + 3) * NPIX];
      short4 hv;
      hv.x = f2bf((v0 - mm) * rr * gam[c + 0] + bet[c + 0]);
      hv.y = f2bf((v1 - mm) * rr * gam[c + 1] + bet[c + 1]);
      hv.z = f2bf((v2 - mm) * rr * gam[c + 2] + bet[c + 2]);
      hv.w = f2bf((v3 - mm) * rr * gam[c + 3] + bet[c + 3]);
      *(short4*)&As[mloc * BKP + kl] = hv;
    }
    #pragma unroll
    for (int p = 0; p < 8; p++) {
      int r = (p << 4) + (t >> 4);
      int cc = (t & 15) << 2;
      float4 w4 = *(const float4*)(wbase + (size_t)(drow0 + r) * 256 + c0 + cc);
      short4 hv;
      hv.x = f2bf(w4.x); hv.y = f2bf(w4.y); hv.z = f2bf(w4.z); hv.w = f2bf(w4.w);
      *(short4*)&Bs[r * BKP + cc] = hv;
    }
    __syncthreads();
    #pragma unroll
    for (int kk = 0; kk < 64; kk += 32) {
      bf16x8 af[4], bfr[4];
      #pragma unroll
      for (int i = 0; i < 4; i++)
        af[i] = *(const bf16x8*)&As[(wm * 64 + i * 16 + lid) * BKP + kk + quad * 8];
      #pragma unroll
      for (int j = 0; j < 4; j++)
        bfr[j] = *(const bf16x8*)&Bs[(wn * 64 + j * 16 + lid) * BKP + kk + quad * 8];
      #pragma unroll
      for (int i = 0; i < 4; i++)
        #pragma unroll
        for (int j = 0; j < 4; j++)
          acc[i][j] = __builtin_amdgcn_mfma_f32_16x16x32_bf16(af[i], bfr[j], acc[i][j], 0, 0, 0);
    }
    __syncthreads();
  }
  #pragma unroll
  for (int i = 0; i < 4; i++) {
    int pl = n0 + wm * 64 + i * 16 + quad * 4;
    #pragma unroll
    for (int j = 0; j < 4; j++) {
      int dim = (nt << 7) + wn * 64 + j * 16 + lid;
      if (nt < 2) {
        #pragma unroll
        for (int r = 0; r < 4; r++)
          kout[((size_t)((b << 10) + pl + r)) * 256 + dim] = f2bf(acc[i][j][r]);
      } else {
        short4 hv;
        hv.x = f2bf(acc[i][j][0]); hv.y = f2bf(acc[i][j][1]);
        hv.z = f2bf(acc[i][j][2]); hv.w = f2bf(acc[i][j][3]);
        *(short4*)(vTout + (size_t)b * 262144 + (size_t)(dim - 256) * 1024 + pl) = hv;
      }
    }
  }
}

// ---------------- K3: slot init — slots = slots_mu, LN_s, q0 ----------------
__global__ __launch_bounds__(256) void slot_init(
    const float* __restrict__ slots_mu,
    const float* __restrict__ lsg, const float* __restrict__ lsb,
    const short* __restrict__ wq_b,
    float* __restrict__ slbuf, short* __restrict__ slbG, short* __restrict__ qb) {
  __shared__ float sl[8][256];
  __shared__ float mus[8], rss[8];
  __shared__ short slnb[8 * SP];
  int b = blockIdx.x, t = threadIdx.x;
  int wave = t >> 6, lane = t & 63, quad = lane >> 4, lid = lane & 15;
  int arow = (lid & 7) * SP, kof0 = quad << 3;
  for (int idx = t; idx < 2048; idx += 256) {
    float v = slots_mu[idx];
    sl[idx >> 8][idx & 255] = v;
    slbuf[(b << 11) + idx] = v;
    slbG[(b << 11) + idx] = f2bf(v);
  }
  __syncthreads();
  {
    int s0 = (wave << 1) + (lane >> 5);
    int l32 = lane & 31;
    float a0 = 0.f, a1 = 0.f;
    #pragma unroll
    for (int j = 0; j < 8; j++) { float v = sl[s0][l32 + (j << 5)]; a0 += v; a1 += v * v; }
    #pragma unroll
    for (int m = 1; m < 32; m <<= 1) { a0 += __shfl_xor(a0, m); a1 += __shfl_xor(a1, m); }
    if (l32 == 0) {
      float mn = a0 * (1.f / 256.f);
      float var = a1 * (1.f / 256.f) - mn * mn;
      mus[s0] = mn; rss[s0] = rsqrtf(var + EPSV);
    }
  }
  __syncthreads();
  for (int idx = t; idx < 2048; idx += 256) {
    int s = idx >> 8, c = idx & 255;
    slnb[s * SP + c] = f2bf((sl[s][c] - mus[s]) * rss[s] * lsg[c] + lsb[c]);
  }
  __syncthreads();
  #pragma unroll
  for (int nt = 0; nt < 4; nt++) {
    int d = (wave << 6) + (nt << 4) + lid;
    f32x4 qa = 0.f;
    #pragma unroll
    for (int ks = 0; ks < 8; ks++) {
      bf16x8 a = *(const bf16x8*)&slnb[arow + (ks << 5) + kof0];
      bf16x8 bb = *(const bf16x8*)(wq_b + (size_t)d * 256 + (ks << 5) + kof0);
      qa = __builtin_amdgcn_mfma_f32_16x16x32_bf16(a, bb, qa, 0, 0, 0);
    }
    #pragma unroll
    for (int r = 0; r < 4; r++) {
      int s = (quad << 2) + r;
      if (s < 8) qb[(b << 11) + (s << 8) + d] = f2bf(qa[r]);
    }
  }
}

// ---------------- K4: heavy — logits + softmax + partial updates ------------
// grid (8 chunks, 64 b), block 256. chunk = 128 pixels.
__global__ __launch_bounds__(256) void attn_heavy(
    const short* __restrict__ kbuf, const short* __restrict__ vT,
    const short* __restrict__ qb,
    float* __restrict__ partials, float* __restrict__ out_attn, int write_attn) {
  __shared__ short attT[8 * AP];
  int chunk = blockIdx.x, b = blockIdx.y;
  int t = threadIdx.x, wave = t >> 6, lane = t & 63, quad = lane >> 4, lid = lane & 15;
  int kof0 = quad << 3;
  // q fragments in registers (slot = lid&7, dup 8->16)
  bf16x8 qf[8];
  const short* qpb = qb + ((size_t)b << 11) + (lid & 7) * 256 + kof0;
  #pragma unroll
  for (int ks = 0; ks < 8; ks++) qf[ks] = *(const bf16x8*)(qpb + (ks << 5));
  // logits + softmax: 2 m-tiles of 16 pixels per wave
  #pragma unroll
  for (int mt = 0; mt < 2; mt++) {
    int p0l = (wave << 5) + (mt << 4);
    const short* kb = kbuf + ((size_t)((b << 10) + (chunk << 7) + p0l + lid)) * 256 + kof0;
    f32x4 la = 0.f;
    #pragma unroll
    for (int ks = 0; ks < 8; ks++) {
      bf16x8 a = *(const bf16x8*)(kb + (ks << 5));
      la = __builtin_amdgcn_mfma_f32_16x16x32_bf16(a, qf[ks], la, 0, 0, 0);
    }
    #pragma unroll
    for (int r = 0; r < 4; r++) {
      float lg = la[r] * 0.0625f;
      float mx = lg;
      #pragma unroll
      for (int m = 1; m < 16; m <<= 1) mx = fmaxf(mx, __shfl_xor(mx, m));
      float e = __expf(lg - mx);
      float sm = e;
      #pragma unroll
      for (int m = 1; m < 16; m <<= 1) sm += __shfl_xor(sm, m);
      float at = (e + e) / sm;          // 16 cols hold each slot twice
      if (lid < 8) {
        int pl = p0l + (quad << 2) + r;
        attT[lid * AP + pl] = f2bf(at);
        if (write_attn) {
          int p = (chunk << 7) + pl;
          out_attn[((size_t)b << 13) + (p << 3) + lid] = at;
        }
      }
    }
  }
  __syncthreads();
  // partial updates = attn^T @ v over this chunk's 128 pixels
  #pragma unroll
  for (int nt = 0; nt < 4; nt++) {
    int d0 = (wave << 6) + (nt << 4);
    f32x4 ua = 0.f;
    #pragma unroll
    for (int ks = 0; ks < 4; ks++) {
      bf16x8 a = *(const bf16x8*)&attT[(lid & 7) * AP + (ks << 5) + kof0];
      bf16x8 bb = *(const bf16x8*)(vT + (size_t)b * 262144 + (size_t)(d0 + lid) * 1024
                                   + (chunk << 7) + (ks << 5) + kof0);
      ua = __builtin_amdgcn_mfma_f32_16x16x32_bf16(a, bb, ua, 0, 0, 0);
    }
    #pragma unroll
    for (int r = 0; r < 4; r++) {
      int s = (quad << 2) + r;
      if (s < 8)
        partials[(((size_t)(b << 3) + chunk) << 11) + (s << 8) + d0 + lid] = ua[r];
    }
  }
}

// ---------------- K5: reduce partials + GRU + MLP + (LN_s + q next) ---------
__global__ __launch_bounds__(256) void slot_reduce(
    const float* __restrict__ partials,
    float* __restrict__ slbuf, short* __restrict__ slbG, short* __restrict__ qb,
    const short* __restrict__ wih_b, const short* __restrict__ whh_b,
    const float* __restrict__ bih, const float* __restrict__ bhh,
    const float* __restrict__ lmg, const float* __restrict__ lmb,
    const short* __restrict__ w1_b, const float* __restrict__ b1,
    const short* __restrict__ w2_b, const float* __restrict__ b2,
    const float* __restrict__ lsg, const float* __restrict__ lsb,
    const short* __restrict__ wq_b,
    float* __restrict__ out, int last) {
  __shared__ float sl[8][256];
  __shared__ float mus[8], rss[8];
  __shared__ short updb[8 * SP], slb_l[8 * SP], lnmb[8 * SP], hmb[8 * SP], slnb[8 * SP];
  int b = blockIdx.x, t = threadIdx.x;
  int wave = t >> 6, lane = t & 63, quad = lane >> 4, lid = lane & 15;
  int arow = (lid & 7) * SP, kof0 = quad << 3;
  // 1. reduce partials over 8 chunks; load slots
  for (int idx = t; idx < 2048; idx += 256) {
    float sum = 0.f;
    #pragma unroll
    for (int c = 0; c < 8; c++) sum += partials[(((size_t)(b << 3) + c) << 11) + idx];
    int s = idx >> 8, dd = idx & 255;
    updb[s * SP + dd] = f2bf(sum);
    sl[s][dd] = slbuf[(b << 11) + idx];
    slb_l[s * SP + dd] = slbG[(b << 11) + idx];
  }
  __syncthreads();
  // 2. GRU via MFMA
  #pragma unroll
  for (int nt = 0; nt < 4; nt++) {
    int d = (wave << 6) + (nt << 4) + lid;
    f32x4 gi[3], gh[3];
    #pragma unroll
    for (int g = 0; g < 3; g++) { gi[g] = 0.f; gh[g] = 0.f; }
    #pragma unroll
    for (int ks = 0; ks < 8; ks++) {
      bf16x8 au  = *(const bf16x8*)&updb [arow + (ks << 5) + kof0];
      bf16x8 as2 = *(const bf16x8*)&slb_l[arow + (ks << 5) + kof0];
      #pragma unroll
      for (int g = 0; g < 3; g++) {
        bf16x8 bi = *(const bf16x8*)(wih_b + (size_t)((g << 8) + d) * 256 + (ks << 5) + kof0);
        bf16x8 bh = *(const bf16x8*)(whh_b + (size_t)((g << 8) + d) * 256 + (ks << 5) + kof0);
        gi[g] = __builtin_amdgcn_mfma_f32_16x16x32_bf16(au,  bi, gi[g], 0, 0, 0);
        gh[g] = __builtin_amdgcn_mfma_f32_16x16x32_bf16(as2, bh, gh[g], 0, 0, 0);
      }
    }
    float bi0 = bih[d], bi1 = bih[256 + d], bi2 = bih[512 + d];
    float bh0 = bhh[d], bh1 = bhh[256 + d], bh2 = bhh[512 + d];
    #pragma unroll
    for (int r = 0; r < 4; r++) {
      int s = (quad << 2) + r;
      if (s < 8) {
        float rg = 1.f / (1.f + __expf(-(gi[0][r] + bi0 + gh[0][r] + bh0)));
        float zg = 1.f / (1.f + __expf(-(gi[1][r] + bi1 + gh[1][r] + bh1)));
        float ng = tanhf(gi[2][r] + bi2 + rg * (gh[2][r] + bh2));
        sl[s][d] = (1.f - zg) * ng + zg * sl[s][d];
      }
    }
  }
  __syncthreads();
  // 3. LN_m
  {
    int s0 = (wave << 1) + (lane >> 5);
    int l32 = lane & 31;
    float a0 = 0.f, a1 = 0.f;
    #pragma unroll
    for (int j = 0; j < 8; j++) { float v = sl[s0][l32 + (j << 5)]; a0 += v; a1 += v * v; }
    #pragma unroll
    for (int m = 1; m < 32; m <<= 1) { a0 += __shfl_xor(a0, m); a1 += __shfl_xor(a1, m); }
    if (l32 == 0) {
      float mn = a0 * (1.f / 256.f);
      float var = a1 * (1.f / 256.f) - mn * mn;
      mus[s0] = mn; rss[s0] = rsqrtf(var + EPSV);
    }
  }
  __syncthreads();
  for (int idx = t; idx < 2048; idx += 256) {
    int s = idx >> 8, c = idx & 255;
    lnmb[s * SP + c] = f2bf((sl[s][c] - mus[s]) * rss[s] * lmg[c] + lmb[c]);
  }
  __syncthreads();
  // 4. MLP layer 1
  #pragma unroll
  for (int nt = 0; nt < 4; nt++) {
    int d = (wave << 6) + (nt << 4) + lid;
    f32x4 ha = 0.f;
    #pragma unroll
    for (int ks = 0; ks < 8; ks++) {
      bf16x8 a = *(const bf16x8*)&lnmb[arow + (ks << 5) + kof0];
      bf16x8 bb = *(const bf16x8*)(w1_b + (size_t)d * 256 + (ks << 5) + kof0);
      ha = __builtin_amdgcn_mfma_f32_16x16x32_bf16(a, bb, ha, 0, 0, 0);
    }
    float bb1 = b1[d];
    #pragma unroll
    for (int r = 0; r < 4; r++) {
      int s = (quad << 2) + r;
      if (s < 8) hmb[s * SP + d] = f2bf(fmaxf(ha[r] + bb1, 0.f));
    }
  }
  __syncthreads();
  // 5. MLP layer 2 + residual
  #pragma unroll
  for (int nt = 0; nt < 4; nt++) {
    int d = (wave << 6) + (nt << 4) + lid;
    f32x4 oa = 0.f;
    #pragma unroll
    for (int ks = 0; ks < 8; ks++) {
      bf16x8 a = *(const bf16x8*)&hmb[arow + (ks << 5) + kof0];
      bf16x8 bb = *(const bf16x8*)(w2_b + (size_t)d * 256 + (ks << 5) + kof0);
      oa = __builtin_amdgcn_mfma_f32_16x16x32_bf16(a, bb, oa, 0, 0, 0);
    }
    float bb2 = b2[d];
    #pragma unroll
    for (int r = 0; r < 4; r++) {
      int s = (quad << 2) + r;
      if (s < 8) sl[s][d] = sl[s][d] + oa[r] + bb2;
    }
  }
  __syncthreads();
  if (last) {
    for (int idx = t; idx < 2048; idx += 256)
      out[(b << 11) + idx] = sl[idx >> 8][idx & 255];
    return;
  }
  // 6. write slots; LN_s + q for next iteration
  for (int idx = t; idx < 2048; idx += 256) {
    float v = sl[idx >> 8][idx & 255];
    slbuf[(b << 11) + idx] = v;
    slbG[(b << 11) + idx] = f2bf(v);
  }
  {
    int s0 = (wave << 1) + (lane >> 5);
    int l32 = lane & 31;
    float a0 = 0.f, a1 = 0.f;
    #pragma unroll
    for (int j = 0; j < 8; j++) { float v = sl[s0][l32 + (j << 5)]; a0 += v; a1 += v * v; }
    #pragma unroll
    for (int m = 1; m < 32; m <<= 1) { a0 += __shfl_xor(a0, m); a1 += __shfl_xor(a1, m); }
    if (l32 == 0) {
      float mn = a0 * (1.f / 256.f);
      float var = a1 * (1.f / 256.f) - mn * mn;
      mus[s0] = mn; rss[s0] = rsqrtf(var + EPSV);
    }
  }
  __syncthreads();
  for (int idx = t; idx < 2048; idx += 256) {
    int s = idx >> 8, c = idx & 255;
    slnb[s * SP + c] = f2bf((sl[s][c] - mus[s]) * rss[s] * lsg[c] + lsb[c]);
  }
  __syncthreads();
  #pragma unroll
  for (int nt = 0; nt < 4; nt++) {
    int d = (wave << 6) + (nt << 4) + lid;
    f32x4 qa = 0.f;
    #pragma unroll
    for (int ks = 0; ks < 8; ks++) {
      bf16x8 a = *(const bf16x8*)&slnb[arow + (ks << 5) + kof0];
      bf16x8 bb = *(const bf16x8*)(wq_b + (size_t)d * 256 + (ks << 5) + kof0);
      qa = __builtin_amdgcn_mfma_f32_16x16x32_bf16(a, bb, qa, 0, 0, 0);
    }
    #pragma unroll
    for (int r = 0; r < 4; r++) {
      int s = (quad << 2) + r;
      if (s < 8) qb[(b << 11) + (s << 8) + d] = f2bf(qa[r]);
    }
  }
}

extern "C" void kernel_launch(void* const* d_in, const int* in_sizes, int n_in,
                              void* d_out, int out_size, void* d_ws, size_t ws_size,
                              hipStream_t stream) {
  const float* x        = (const float*)d_in[0];
  const float* slots_mu = (const float*)d_in[1];
  const float* ln_in_g  = (const float*)d_in[2];
  const float* ln_in_b  = (const float*)d_in[3];
  const float* wk       = (const float*)d_in[4];
  const float* wv       = (const float*)d_in[5];
  const float* ln_s_g   = (const float*)d_in[6];
  const float* ln_s_b   = (const float*)d_in[7];
  const float* wq       = (const float*)d_in[8];
  const float* wih      = (const float*)d_in[9];
  const float* whh      = (const float*)d_in[10];
  const float* bih      = (const float*)d_in[11];
  const float* bhh      = (const float*)d_in[12];
  const float* lmg      = (const float*)d_in[13];
  const float* lmb      = (const float*)d_in[14];
  const float* w1       = (const float*)d_in[15];
  const float* b1       = (const float*)d_in[16];
  const float* w2       = (const float*)d_in[17];
  const float* b2       = (const float*)d_in[18];
  float* out = (float*)d_out;
  float* out_attn = out + 131072;

  char* ws = (char*)d_ws;
  short* kbuf   = (short*)(ws);                  // 33,554,432 B
  short* vT     = (short*)(ws + 33554432);       // 33,554,432 B
  float* mu     = (float*)(ws + 67108864);       // 262,144 B
  float* rstd   = (float*)(ws + 67371008);       // 262,144 B
  short* wq_b   = (short*)(ws + 67633152);       // 131,072 B
  short* wih_b  = (short*)(ws + 67764224);       // 393,216 B
  short* whh_b  = (short*)(ws + 68157440);       // 393,216 B
  short* w1_b   = (short*)(ws + 68550656);       // 131,072 B
  short* w2_b   = (short*)(ws + 68681728);       // 131,072 B
  float* slbuf  = (float*)(ws + 68812800);       // 524,288 B fp32 slots
  short* slbG   = (short*)(ws + 69337088);       // 262,144 B bf16 slots
  short* qb     = (short*)(ws + 69599232);       // 262,144 B bf16 q
  float* parts  = (float*)(ws + 69861376);       // 4,194,304 B fp32 partials -> 74,055,680

  wcvt<<<2304, 256, 0, stream>>>(wq, wih, whh, w1, w2, wq_b, wih_b, whh_b, w1_b, w2_b);
  ln_stats<<<256, 256, 0, stream>>>(x, mu, rstd);
  kv_gemm<<<2048, 256, 0, stream>>>(x, mu, rstd, ln_in_g, ln_in_b, wk, wv, kbuf, vT);
  slot_init<<<64, 256, 0, stream>>>(slots_mu, ln_s_g, ln_s_b, wq_b, slbuf, slbG, qb);
  for (int it = 0; it < 3; it++) {
    attn_heavy<<<dim3(8, 64), 256, 0, stream>>>(kbuf, vT, qb, parts, out_attn,
                                                (it == 2) ? 1 : 0);
    slot_reduce<<<64, 256, 0, stream>>>(parts, slbuf, slbG, qb,
                                        wih_b, whh_b, bih, bhh, lmg, lmb,
                                        w1_b, b1, w2_b, b2, ln_s_g, ln_s_b, wq_b,
                                        out, (it == 2) ? 1 : 0);
  }
}

// Round 3
// 382.378 us; speedup vs baseline: 1.5044x; 1.1697x over previous
//
#include <hip/hip_runtime.h>

#define NPIX 1024
#define CIN  256
#define EPSV 1e-5f
#define SP 264
#define AP 72
#define BKA 264

typedef __attribute__((ext_vector_type(8))) short bf16x8;
typedef __attribute__((ext_vector_type(4))) float f32x4;

__device__ __forceinline__ short f2bf(float f) {
  unsigned u = __float_as_uint(f);
  unsigned r = (u + 0x7FFFu + ((u >> 16) & 1u)) >> 16;
  return (short)r;
}
__device__ __forceinline__ float b2f(short s) {
  return __uint_as_float(((unsigned)(unsigned short)s) << 16);
}

// ---------------- K0: weights fp32 -> bf16 ----------------------------------
__global__ __launch_bounds__(256) void wcvt(
    const float* __restrict__ wk, const float* __restrict__ wv,
    const float* __restrict__ wq, const float* __restrict__ wih,
    const float* __restrict__ whh, const float* __restrict__ w1,
    const float* __restrict__ w2,
    short* __restrict__ wkv_b, short* __restrict__ wq_b,
    short* __restrict__ wih_b, short* __restrict__ whh_b,
    short* __restrict__ w1_b, short* __restrict__ w2_b) {
  int id = blockIdx.x * 256 + threadIdx.x;
  if      (id <  65536) wkv_b[id         ] = f2bf(wk [id         ]);
  else if (id < 131072) wkv_b[id         ] = f2bf(wv [id - 131072 + 65536]);
  else if (id < 196608) wq_b [id - 131072] = f2bf(wq [id - 131072]);
  else if (id < 393216) wih_b[id - 196608] = f2bf(wih[id - 196608]);
  else if (id < 589824) whh_b[id - 393216] = f2bf(whh[id - 393216]);
  else if (id < 655360) w1_b [id - 589824] = f2bf(w1 [id - 589824]);
  else if (id < 720896) w2_b [id - 655360] = f2bf(w2 [id - 655360]);
}

// ---------------- K1: fused LN-stats + LN + [k|v] projection ----------------
// grid 512 = 64 b x 8 pixel-tiles(128). Block 256 (4 waves, 2x2).
// A-tile (128 pix x 256 c) staged once in LDS (LN'd, bf16); B frags direct
// from global bf16 weights; nt=0..3 loops 4x128 output dims on one acc set.
__global__ __launch_bounds__(256, 2) void kv_gemm(
    const float* __restrict__ x,
    const float* __restrict__ gam, const float* __restrict__ bet,
    const short* __restrict__ wkv,
    short* __restrict__ kout, short* __restrict__ vTout) {
  __shared__ __align__(16) short As[128 * BKA];
  __shared__ float ps[2][128], pq[2][128], mus[128], rss[128];
  int t = threadIdx.x;
  int bid = blockIdx.x;
  int pt = bid & 7, b = bid >> 3;
  int n0 = pt << 7;
  int mloc = t & 127, grp = t >> 7;
  const float* xb = x + (size_t)b * CIN * NPIX + n0 + mloc;
  // pass 1: LN stats (each thread: 128 channels of its pixel)
  {
    float s = 0.f, sq = 0.f;
    int cbase = grp << 7;
    #pragma unroll 8
    for (int i = 0; i < 128; i++) {
      float v = xb[(size_t)(cbase + i) * NPIX];
      s += v; sq += v * v;
    }
    ps[grp][mloc] = s; pq[grp][mloc] = sq;
  }
  __syncthreads();
  if (t < 128) {
    float s = ps[0][t] + ps[1][t];
    float sq = pq[0][t] + pq[1][t];
    float m = s * (1.f / 256.f);
    float var = sq * (1.f / 256.f) - m * m;
    mus[t] = m; rss[t] = rsqrtf(var + EPSV);
  }
  __syncthreads();
  float mm = mus[mloc], rr = rss[mloc];
  // pass 2: stage LN'd bf16 A-tile (x re-read is L2/L3-hot)
  #pragma unroll
  for (int kt = 0; kt < 4; kt++) {
    #pragma unroll
    for (int p = 0; p < 8; p++) {
      int kl = (p << 3) + (grp << 2);
      int c = (kt << 6) + kl;
      float v0 = xb[(size_t)(c + 0) * NPIX];
      float v1 = xb[(size_t)(c + 1) * NPIX];
      float v2 = xb[(size_t)(c + 2) * NPIX];
      float v3 = xb[(size_t)(c + 3) * NPIX];
      short4 hv;
      hv.x = f2bf((v0 - mm) * rr * gam[c + 0] + bet[c + 0]);
      hv.y = f2bf((v1 - mm) * rr * gam[c + 1] + bet[c + 1]);
      hv.z = f2bf((v2 - mm) * rr * gam[c + 2] + bet[c + 2]);
      hv.w = f2bf((v3 - mm) * rr * gam[c + 3] + bet[c + 3]);
      *(short4*)&As[mloc * BKA + c] = hv;
    }
  }
  __syncthreads();
  int w = t >> 6, lane = t & 63, quad = lane >> 4, lid = lane & 15;
  int wm = w & 1, wn = w >> 1;
  #pragma unroll
  for (int nt = 0; nt < 4; nt++) {
    f32x4 acc[4][4];
    #pragma unroll
    for (int i = 0; i < 4; i++)
      #pragma unroll
      for (int j = 0; j < 4; j++) acc[i][j] = 0.f;
    #pragma unroll
    for (int ks = 0; ks < 8; ks++) {
      int kof = (ks << 5) + (quad << 3);
      bf16x8 af[4], bfr[4];
      #pragma unroll
      for (int i = 0; i < 4; i++)
        af[i] = *(const bf16x8*)&As[(wm * 64 + i * 16 + lid) * BKA + kof];
      #pragma unroll
      for (int j = 0; j < 4; j++)
        bfr[j] = *(const bf16x8*)(wkv + (size_t)((nt << 7) + wn * 64 + j * 16 + lid) * 256 + kof);
      #pragma unroll
      for (int i = 0; i < 4; i++)
        #pragma unroll
        for (int j = 0; j < 4; j++)
          acc[i][j] = __builtin_amdgcn_mfma_f32_16x16x32_bf16(af[i], bfr[j], acc[i][j], 0, 0, 0);
    }
    #pragma unroll
    for (int i = 0; i < 4; i++) {
      int pl = wm * 64 + i * 16 + (quad << 2);
      #pragma unroll
      for (int j = 0; j < 4; j++) {
        int dim = (nt << 7) + wn * 64 + j * 16 + lid;
        if (nt < 2) {
          #pragma unroll
          for (int r = 0; r < 4; r++)
            kout[((size_t)((b << 10) + n0 + pl + r)) * 256 + dim] = f2bf(acc[i][j][r]);
        } else {
          short4 hv;
          hv.x = f2bf(acc[i][j][0]); hv.y = f2bf(acc[i][j][1]);
          hv.z = f2bf(acc[i][j][2]); hv.w = f2bf(acc[i][j][3]);
          *(short4*)(vTout + (size_t)b * 262144 + (size_t)(dim - 256) * 1024 + n0 + pl) = hv;
        }
      }
    }
  }
}

// ---------------- K3: slot init — slots = slots_mu, LN_s, q0 ----------------
__global__ __launch_bounds__(256) void slot_init(
    const float* __restrict__ slots_mu,
    const float* __restrict__ lsg, const float* __restrict__ lsb,
    const short* __restrict__ wq_b,
    float* __restrict__ slbuf, short* __restrict__ slbG, short* __restrict__ qb) {
  __shared__ float sl[8][256];
  __shared__ float mus[8], rss[8];
  __shared__ __align__(16) short slnb[8 * SP];
  int b = blockIdx.x, t = threadIdx.x;
  int wave = t >> 6, lane = t & 63, quad = lane >> 4, lid = lane & 15;
  int arow = (lid & 7) * SP, kof0 = quad << 3;
  for (int idx = t; idx < 2048; idx += 256) {
    float v = slots_mu[idx];
    sl[idx >> 8][idx & 255] = v;
    slbuf[(b << 11) + idx] = v;
    slbG[(b << 11) + idx] = f2bf(v);
  }
  __syncthreads();
  {
    int s0 = (wave << 1) + (lane >> 5);
    int l32 = lane & 31;
    float a0 = 0.f, a1 = 0.f;
    #pragma unroll
    for (int j = 0; j < 8; j++) { float v = sl[s0][l32 + (j << 5)]; a0 += v; a1 += v * v; }
    #pragma unroll
    for (int m = 1; m < 32; m <<= 1) { a0 += __shfl_xor(a0, m); a1 += __shfl_xor(a1, m); }
    if (l32 == 0) {
      float mn = a0 * (1.f / 256.f);
      float var = a1 * (1.f / 256.f) - mn * mn;
      mus[s0] = mn; rss[s0] = rsqrtf(var + EPSV);
    }
  }
  __syncthreads();
  for (int idx = t; idx < 2048; idx += 256) {
    int s = idx >> 8, c = idx & 255;
    slnb[s * SP + c] = f2bf((sl[s][c] - mus[s]) * rss[s] * lsg[c] + lsb[c]);
  }
  __syncthreads();
  #pragma unroll
  for (int nt = 0; nt < 4; nt++) {
    int d = (wave << 6) + (nt << 4) + lid;
    f32x4 qa = 0.f;
    #pragma unroll
    for (int ks = 0; ks < 8; ks++) {
      bf16x8 a = *(const bf16x8*)&slnb[arow + (ks << 5) + kof0];
      bf16x8 bb = *(const bf16x8*)(wq_b + (size_t)d * 256 + (ks << 5) + kof0);
      qa = __builtin_amdgcn_mfma_f32_16x16x32_bf16(a, bb, qa, 0, 0, 0);
    }
    #pragma unroll
    for (int r = 0; r < 4; r++) {
      int s = (quad << 2) + r;
      if (s < 8) qb[(b << 11) + (s << 8) + d] = f2bf(qa[r]);
    }
  }
}

// ---------------- K4: heavy — logits + softmax + partial updates ------------
// grid (16 chunks, 64 b), block 256. chunk = 64 pixels.
__global__ __launch_bounds__(256) void attn_heavy(
    const short* __restrict__ kbuf, const short* __restrict__ vT,
    const short* __restrict__ qb,
    short* __restrict__ partials, float* __restrict__ out_attn, int write_attn) {
  __shared__ __align__(16) short attT[8 * AP];
  int chunk = blockIdx.x, b = blockIdx.y;
  int t = threadIdx.x, wave = t >> 6, lane = t & 63, quad = lane >> 4, lid = lane & 15;
  int kof0 = quad << 3;
  bf16x8 qf[8];
  const short* qpb = qb + ((size_t)b << 11) + (lid & 7) * 256 + kof0;
  #pragma unroll
  for (int ks = 0; ks < 8; ks++) qf[ks] = *(const bf16x8*)(qpb + (ks << 5));
  // logits + softmax: one 16-pixel tile per wave
  {
    int p0l = wave << 4;
    const short* kb = kbuf + ((size_t)((b << 10) + (chunk << 6) + p0l + lid)) * 256 + kof0;
    f32x4 la = 0.f;
    #pragma unroll
    for (int ks = 0; ks < 8; ks++) {
      bf16x8 a = *(const bf16x8*)(kb + (ks << 5));
      la = __builtin_amdgcn_mfma_f32_16x16x32_bf16(a, qf[ks], la, 0, 0, 0);
    }
    #pragma unroll
    for (int r = 0; r < 4; r++) {
      float lg = la[r] * 0.0625f;
      float mx = lg;
      #pragma unroll
      for (int m = 1; m < 16; m <<= 1) mx = fmaxf(mx, __shfl_xor(mx, m));
      float e = __expf(lg - mx);
      float sm = e;
      #pragma unroll
      for (int m = 1; m < 16; m <<= 1) sm += __shfl_xor(sm, m);
      float at = (e + e) / sm;          // 16 cols hold each slot twice
      if (lid < 8) {
        int pl = p0l + (quad << 2) + r;
        attT[lid * AP + pl] = f2bf(at);
        if (write_attn) {
          int p = (chunk << 6) + pl;
          out_attn[((size_t)b << 13) + (p << 3) + lid] = at;
        }
      }
    }
  }
  __syncthreads();
  // partial updates = attn^T @ v over this chunk's 64 pixels
  #pragma unroll
  for (int nt = 0; nt < 4; nt++) {
    int d0 = (wave << 6) + (nt << 4);
    f32x4 ua = 0.f;
    #pragma unroll
    for (int ks = 0; ks < 2; ks++) {
      bf16x8 a = *(const bf16x8*)&attT[(lid & 7) * AP + (ks << 5) + kof0];
      bf16x8 bb = *(const bf16x8*)(vT + (size_t)b * 262144 + (size_t)(d0 + lid) * 1024
                                   + (chunk << 6) + (ks << 5) + kof0);
      ua = __builtin_amdgcn_mfma_f32_16x16x32_bf16(a, bb, ua, 0, 0, 0);
    }
    #pragma unroll
    for (int r = 0; r < 4; r++) {
      int s = (quad << 2) + r;
      if (s < 8)
        partials[(((size_t)(b << 4) + chunk) << 11) + (s << 8) + d0 + lid] = f2bf(ua[r]);
    }
  }
}

// ---------------- K5: reduce partials + GRU + MLP + (LN_s + q next) ---------
__global__ __launch_bounds__(256) void slot_reduce(
    const short* __restrict__ partials,
    float* __restrict__ slbuf, short* __restrict__ slbG, short* __restrict__ qb,
    const short* __restrict__ wih_b, const short* __restrict__ whh_b,
    const float* __restrict__ bih, const float* __restrict__ bhh,
    const float* __restrict__ lmg, const float* __restrict__ lmb,
    const short* __restrict__ w1_b, const float* __restrict__ b1,
    const short* __restrict__ w2_b, const float* __restrict__ b2,
    const float* __restrict__ lsg, const float* __restrict__ lsb,
    const short* __restrict__ wq_b,
    float* __restrict__ out, int last) {
  __shared__ float sl[8][256];
  __shared__ float mus[8], rss[8];
  __shared__ __align__(16) short updb[8 * SP], slb_l[8 * SP], lnmb[8 * SP],
                                  hmb[8 * SP], slnb[8 * SP];
  int b = blockIdx.x, t = threadIdx.x;
  int wave = t >> 6, lane = t & 63, quad = lane >> 4, lid = lane & 15;
  int arow = (lid & 7) * SP, kof0 = quad << 3;
  for (int idx = t; idx < 2048; idx += 256) {
    float sum = 0.f;
    #pragma unroll
    for (int c = 0; c < 16; c++) sum += b2f(partials[(((size_t)(b << 4) + c) << 11) + idx]);
    int s = idx >> 8, dd = idx & 255;
    updb[s * SP + dd] = f2bf(sum);
    sl[s][dd] = slbuf[(b << 11) + idx];
    slb_l[s * SP + dd] = slbG[(b << 11) + idx];
  }
  __syncthreads();
  // GRU via MFMA
  #pragma unroll
  for (int nt = 0; nt < 4; nt++) {
    int d = (wave << 6) + (nt << 4) + lid;
    f32x4 gi[3], gh[3];
    #pragma unroll
    for (int g = 0; g < 3; g++) { gi[g] = 0.f; gh[g] = 0.f; }
    #pragma unroll
    for (int ks = 0; ks < 8; ks++) {
      bf16x8 au  = *(const bf16x8*)&updb [arow + (ks << 5) + kof0];
      bf16x8 as2 = *(const bf16x8*)&slb_l[arow + (ks << 5) + kof0];
      #pragma unroll
      for (int g = 0; g < 3; g++) {
        bf16x8 bi = *(const bf16x8*)(wih_b + (size_t)((g << 8) + d) * 256 + (ks << 5) + kof0);
        bf16x8 bh = *(const bf16x8*)(whh_b + (size_t)((g << 8) + d) * 256 + (ks << 5) + kof0);
        gi[g] = __builtin_amdgcn_mfma_f32_16x16x32_bf16(au,  bi, gi[g], 0, 0, 0);
        gh[g] = __builtin_amdgcn_mfma_f32_16x16x32_bf16(as2, bh, gh[g], 0, 0, 0);
      }
    }
    float bi0 = bih[d], bi1 = bih[256 + d], bi2 = bih[512 + d];
    float bh0 = bhh[d], bh1 = bhh[256 + d], bh2 = bhh[512 + d];
    #pragma unroll
    for (int r = 0; r < 4; r++) {
      int s = (quad << 2) + r;
      if (s < 8) {
        float rg = 1.f / (1.f + __expf(-(gi[0][r] + bi0 + gh[0][r] + bh0)));
        float zg = 1.f / (1.f + __expf(-(gi[1][r] + bi1 + gh[1][r] + bh1)));
        float ng = tanhf(gi[2][r] + bi2 + rg * (gh[2][r] + bh2));
        sl[s][d] = (1.f - zg) * ng + zg * sl[s][d];
      }
    }
  }
  __syncthreads();
  // LN_m
  {
    int s0 = (wave << 1) + (lane >> 5);
    int l32 = lane & 31;
    float a0 = 0.f, a1 = 0.f;
    #pragma unroll
    for (int j = 0; j < 8; j++) { float v = sl[s0][l32 + (j << 5)]; a0 += v; a1 += v * v; }
    #pragma unroll
    for (int m = 1; m < 32; m <<= 1) { a0 += __shfl_xor(a0, m); a1 += __shfl_xor(a1, m); }
    if (l32 == 0) {
      float mn = a0 * (1.f / 256.f);
      float var = a1 * (1.f / 256.f) - mn * mn;
      mus[s0] = mn; rss[s0] = rsqrtf(var + EPSV);
    }
  }
  __syncthreads();
  for (int idx = t; idx < 2048; idx += 256) {
    int s = idx >> 8, c = idx & 255;
    lnmb[s * SP + c] = f2bf((sl[s][c] - mus[s]) * rss[s] * lmg[c] + lmb[c]);
  }
  __syncthreads();
  // MLP layer 1
  #pragma unroll
  for (int nt = 0; nt < 4; nt++) {
    int d = (wave << 6) + (nt << 4) + lid;
    f32x4 ha = 0.f;
    #pragma unroll
    for (int ks = 0; ks < 8; ks++) {
      bf16x8 a = *(const bf16x8*)&lnmb[arow + (ks << 5) + kof0];
      bf16x8 bb = *(const bf16x8*)(w1_b + (size_t)d * 256 + (ks << 5) + kof0);
      ha = __builtin_amdgcn_mfma_f32_16x16x32_bf16(a, bb, ha, 0, 0, 0);
    }
    float bb1 = b1[d];
    #pragma unroll
    for (int r = 0; r < 4; r++) {
      int s = (quad << 2) + r;
      if (s < 8) hmb[s * SP + d] = f2bf(fmaxf(ha[r] + bb1, 0.f));
    }
  }
  __syncthreads();
  // MLP layer 2 + residual
  #pragma unroll
  for (int nt = 0; nt < 4; nt++) {
    int d = (wave << 6) + (nt << 4) + lid;
    f32x4 oa = 0.f;
    #pragma unroll
    for (int ks = 0; ks < 8; ks++) {
      bf16x8 a = *(const bf16x8*)&hmb[arow + (ks << 5) + kof0];
      bf16x8 bb = *(const bf16x8*)(w2_b + (size_t)d * 256 + (ks << 5) + kof0);
      oa = __builtin_amdgcn_mfma_f32_16x16x32_bf16(a, bb, oa, 0, 0, 0);
    }
    float bb2 = b2[d];
    #pragma unroll
    for (int r = 0; r < 4; r++) {
      int s = (quad << 2) + r;
      if (s < 8) sl[s][d] = sl[s][d] + oa[r] + bb2;
    }
  }
  __syncthreads();
  if (last) {
    for (int idx = t; idx < 2048; idx += 256)
      out[(b << 11) + idx] = sl[idx >> 8][idx & 255];
    return;
  }
  for (int idx = t; idx < 2048; idx += 256) {
    float v = sl[idx >> 8][idx & 255];
    slbuf[(b << 11) + idx] = v;
    slbG[(b << 11) + idx] = f2bf(v);
  }
  {
    int s0 = (wave << 1) + (lane >> 5);
    int l32 = lane & 31;
    float a0 = 0.f, a1 = 0.f;
    #pragma unroll
    for (int j = 0; j < 8; j++) { float v = sl[s0][l32 + (j << 5)]; a0 += v; a1 += v * v; }
    #pragma unroll
    for (int m = 1; m < 32; m <<= 1) { a0 += __shfl_xor(a0, m); a1 += __shfl_xor(a1, m); }
    if (l32 == 0) {
      float mn = a0 * (1.f / 256.f);
      float var = a1 * (1.f / 256.f) - mn * mn;
      mus[s0] = mn; rss[s0] = rsqrtf(var + EPSV);
    }
  }
  __syncthreads();
  for (int idx = t; idx < 2048; idx += 256) {
    int s = idx >> 8, c = idx & 255;
    slnb[s * SP + c] = f2bf((sl[s][c] - mus[s]) * rss[s] * lsg[c] + lsb[c]);
  }
  __syncthreads();
  #pragma unroll
  for (int nt = 0; nt < 4; nt++) {
    int d = (wave << 6) + (nt << 4) + lid;
    f32x4 qa = 0.f;
    #pragma unroll
    for (int ks = 0; ks < 8; ks++) {
      bf16x8 a = *(const bf16x8*)&slnb[arow + (ks << 5) + kof0];
      bf16x8 bb = *(const bf16x8*)(wq_b + (size_t)d * 256 + (ks << 5) + kof0);
      qa = __builtin_amdgcn_mfma_f32_16x16x32_bf16(a, bb, qa, 0, 0, 0);
    }
    #pragma unroll
    for (int r = 0; r < 4; r++) {
      int s = (quad << 2) + r;
      if (s < 8) qb[(b << 11) + (s << 8) + d] = f2bf(qa[r]);
    }
  }
}

extern "C" void kernel_launch(void* const* d_in, const int* in_sizes, int n_in,
                              void* d_out, int out_size, void* d_ws, size_t ws_size,
                              hipStream_t stream) {
  const float* x        = (const float*)d_in[0];
  const float* slots_mu = (const float*)d_in[1];
  const float* ln_in_g  = (const float*)d_in[2];
  const float* ln_in_b  = (const float*)d_in[3];
  const float* wk       = (const float*)d_in[4];
  const float* wv       = (const float*)d_in[5];
  const float* ln_s_g   = (const float*)d_in[6];
  const float* ln_s_b   = (const float*)d_in[7];
  const float* wq       = (const float*)d_in[8];
  const float* wih      = (const float*)d_in[9];
  const float* whh      = (const float*)d_in[10];
  const float* bih      = (const float*)d_in[11];
  const float* bhh      = (const float*)d_in[12];
  const float* lmg      = (const float*)d_in[13];
  const float* lmb      = (const float*)d_in[14];
  const float* w1       = (const float*)d_in[15];
  const float* b1       = (const float*)d_in[16];
  const float* w2       = (const float*)d_in[17];
  const float* b2       = (const float*)d_in[18];
  float* out = (float*)d_out;
  float* out_attn = out + 131072;

  char* ws = (char*)d_ws;
  short* kbuf   = (short*)(ws);                  // 33,554,432
  short* vT     = (short*)(ws + 33554432);       // 33,554,432
  short* wkv_b  = (short*)(ws + 67108864);       //    262,144
  short* wq_b   = (short*)(ws + 67371008);       //    131,072
  short* wih_b  = (short*)(ws + 67502080);       //    393,216
  short* whh_b  = (short*)(ws + 67895296);       //    393,216
  short* w1_b   = (short*)(ws + 68288512);       //    131,072
  short* w2_b   = (short*)(ws + 68419584);       //    131,072
  float* slbuf  = (float*)(ws + 68550656);       //    524,288
  short* slbG   = (short*)(ws + 69074944);       //    262,144
  short* qb     = (short*)(ws + 69337088);       //    262,144
  short* parts  = (short*)(ws + 69599232);       //  4,194,304 -> 73,793,536

  wcvt<<<2816, 256, 0, stream>>>(wk, wv, wq, wih, whh, w1, w2,
                                 wkv_b, wq_b, wih_b, whh_b, w1_b, w2_b);
  kv_gemm<<<512, 256, 0, stream>>>(x, ln_in_g, ln_in_b, wkv_b, kbuf, vT);
  slot_init<<<64, 256, 0, stream>>>(slots_mu, ln_s_g, ln_s_b, wq_b, slbuf, slbG, qb);
  for (int it = 0; it < 3; it++) {
    attn_heavy<<<dim3(16, 64), 256, 0, stream>>>(kbuf, vT, qb, parts, out_attn,
                                                 (it == 2) ? 1 : 0);
    slot_reduce<<<64, 256, 0, stream>>>(parts, slbuf, slbG, qb,
                                        wih_b, whh_b, bih, bhh, lmg, lmb,
                                        w1_b, b1, w2_b, b2, ln_s_g, ln_s_b, wq_b,
                                        out, (it == 2) ? 1 : 0);
  }
}

// Round 4
// 363.675 us; speedup vs baseline: 1.5817x; 1.0514x over previous
//
#include <hip/hip_runtime.h>

#define NPIX 1024
#define CIN  256
#define EPSV 1e-5f
#define SP 264
#define AP 72
#define BKA 264

typedef __attribute__((ext_vector_type(8))) short bf16x8;
typedef __attribute__((ext_vector_type(4))) float f32x4;

__device__ __forceinline__ short f2bf(float f) {
  unsigned u = __float_as_uint(f);
  unsigned r = (u + 0x7FFFu + ((u >> 16) & 1u)) >> 16;
  return (short)r;
}
__device__ __forceinline__ float b2f(short s) {
  return __uint_as_float(((unsigned)(unsigned short)s) << 16);
}

// ---------------- K0a: non-kv weights fp32 -> bf16 --------------------------
__global__ __launch_bounds__(256) void wcvt(
    const float* __restrict__ wq, const float* __restrict__ wih,
    const float* __restrict__ whh, const float* __restrict__ w1,
    const float* __restrict__ w2,
    short* __restrict__ wq_b, short* __restrict__ wih_b, short* __restrict__ whh_b,
    short* __restrict__ w1_b, short* __restrict__ w2_b) {
  int id = blockIdx.x * 256 + threadIdx.x;
  if      (id <  65536) wq_b [id         ] = f2bf(wq [id         ]);
  else if (id < 262144) wih_b[id -  65536] = f2bf(wih[id -  65536]);
  else if (id < 458752) whh_b[id - 262144] = f2bf(whh[id - 262144]);
  else if (id < 524288) w1_b [id - 458752] = f2bf(w1 [id - 458752]);
  else if (id < 589824) w2_b [id - 524288] = f2bf(w2 [id - 524288]);
}

// ---------------- K0b: wkv' = g*w (bf16) + A=sum(g*w), B=sum(b*w) -----------
__global__ __launch_bounds__(256) void wfold(
    const float* __restrict__ wk, const float* __restrict__ wv,
    const float* __restrict__ g, const float* __restrict__ bet,
    short* __restrict__ wkv_b, float* __restrict__ kvA, float* __restrict__ kvB) {
  __shared__ float ra[4], rb[4];
  int d = blockIdx.x;                 // 0..511
  int t = threadIdx.x;
  const float* wrow = (d < 256) ? (wk + (size_t)d * 256) : (wv + (size_t)(d - 256) * 256);
  float w = wrow[t], gg = g[t], bb = bet[t];
  float pa = gg * w, pb = bb * w;
  wkv_b[(size_t)d * 256 + t] = f2bf(pa);
  #pragma unroll
  for (int m = 1; m < 64; m <<= 1) { pa += __shfl_xor(pa, m); pb += __shfl_xor(pb, m); }
  int wave = t >> 6, lane = t & 63;
  if (lane == 0) { ra[wave] = pa; rb[wave] = pb; }
  __syncthreads();
  if (t == 0) {
    kvA[d] = ra[0] + ra[1] + ra[2] + ra[3];
    kvB[d] = rb[0] + rb[1] + rb[2] + rb[3];
  }
}

// ---------------- K1: single-pass raw-x stage + stats + [k|v] GEMM ----------
// grid 512 = 64 b x 8 pixel-tiles(128). Block 256 (4 waves, 2x2 tiles).
// LN folded: k[p][d] = rstd_p*(acc_pd - mu_p*A_d) + B_d.
__global__ __launch_bounds__(256, 2) void kv_gemm(
    const float* __restrict__ x,
    const short* __restrict__ wkv,
    const float* __restrict__ kvA, const float* __restrict__ kvB,
    short* __restrict__ kout, short* __restrict__ vTout) {
  __shared__ __align__(16) short As[128 * BKA];
  __shared__ float ps[8][128], pq[8][128];
  __shared__ float mus[128], rss[128];
  int t = threadIdx.x;
  int pt = blockIdx.x & 7, b = blockIdx.x >> 3;
  int n0 = pt << 7;
  int row = t >> 5, l32 = t & 31;
  int p4 = l32 << 2;
  const float* xb = x + (size_t)b * CIN * NPIX + n0 + p4;
  float s0 = 0.f, s1 = 0.f, s2 = 0.f, s3 = 0.f;
  float q0 = 0.f, q1 = 0.f, q2 = 0.f, q3 = 0.f;
  // single pass: float4 loads of raw x, stats + bf16 transpose-stage to LDS
  #pragma unroll
  for (int i = 0; i < 32; i++) {
    int c = (i << 3) + row;
    float4 v = *(const float4*)(xb + (size_t)c * NPIX);
    s0 += v.x; s1 += v.y; s2 += v.z; s3 += v.w;
    q0 += v.x * v.x; q1 += v.y * v.y; q2 += v.z * v.z; q3 += v.w * v.w;
    As[(p4 + 0) * BKA + c] = f2bf(v.x);
    As[(p4 + 1) * BKA + c] = f2bf(v.y);
    As[(p4 + 2) * BKA + c] = f2bf(v.z);
    As[(p4 + 3) * BKA + c] = f2bf(v.w);
  }
  ps[row][p4 + 0] = s0; ps[row][p4 + 1] = s1; ps[row][p4 + 2] = s2; ps[row][p4 + 3] = s3;
  pq[row][p4 + 0] = q0; pq[row][p4 + 1] = q1; pq[row][p4 + 2] = q2; pq[row][p4 + 3] = q3;
  __syncthreads();
  if (t < 128) {
    float s = 0.f, sq = 0.f;
    #pragma unroll
    for (int r = 0; r < 8; r++) { s += ps[r][t]; sq += pq[r][t]; }
    float m = s * (1.f / 256.f);
    float var = sq * (1.f / 256.f) - m * m;
    mus[t] = m; rss[t] = rsqrtf(var + EPSV);
  }
  __syncthreads();
  int w = t >> 6, lane = t & 63, quad = lane >> 4, lid = lane & 15;
  int wm = w & 1, wn = w >> 1;
  #pragma unroll
  for (int nt = 0; nt < 4; nt++) {
    f32x4 acc[4][4];
    #pragma unroll
    for (int i = 0; i < 4; i++)
      #pragma unroll
      for (int j = 0; j < 4; j++) acc[i][j] = 0.f;
    #pragma unroll
    for (int ks = 0; ks < 8; ks++) {
      int kof = (ks << 5) + (quad << 3);
      bf16x8 af[4], bfr[4];
      #pragma unroll
      for (int i = 0; i < 4; i++)
        af[i] = *(const bf16x8*)&As[(wm * 64 + i * 16 + lid) * BKA + kof];
      #pragma unroll
      for (int j = 0; j < 4; j++)
        bfr[j] = *(const bf16x8*)(wkv + (size_t)((nt << 7) + wn * 64 + j * 16 + lid) * 256 + kof);
      #pragma unroll
      for (int i = 0; i < 4; i++)
        #pragma unroll
        for (int j = 0; j < 4; j++)
          acc[i][j] = __builtin_amdgcn_mfma_f32_16x16x32_bf16(af[i], bfr[j], acc[i][j], 0, 0, 0);
    }
    #pragma unroll
    for (int i = 0; i < 4; i++) {
      int pl = wm * 64 + i * 16 + (quad << 2);     // local pixel row base
      #pragma unroll
      for (int j = 0; j < 4; j++) {
        int dim = (nt << 7) + wn * 64 + j * 16 + lid;
        float Ad = kvA[dim], Bd = kvB[dim];
        if (nt < 2) {
          #pragma unroll
          for (int r = 0; r < 4; r++) {
            float val = rss[pl + r] * (acc[i][j][r] - mus[pl + r] * Ad) + Bd;
            kout[((size_t)((b << 10) + n0 + pl + r)) * 256 + dim] = f2bf(val);
          }
        } else {
          short4 hv;
          hv.x = f2bf(rss[pl + 0] * (acc[i][j][0] - mus[pl + 0] * Ad) + Bd);
          hv.y = f2bf(rss[pl + 1] * (acc[i][j][1] - mus[pl + 1] * Ad) + Bd);
          hv.z = f2bf(rss[pl + 2] * (acc[i][j][2] - mus[pl + 2] * Ad) + Bd);
          hv.w = f2bf(rss[pl + 3] * (acc[i][j][3] - mus[pl + 3] * Ad) + Bd);
          *(short4*)(vTout + (size_t)b * 262144 + (size_t)(dim - 256) * 1024 + n0 + pl) = hv;
        }
      }
    }
  }
}

// ---------------- K3: slot init — slots = slots_mu, LN_s, q0 ----------------
__global__ __launch_bounds__(256) void slot_init(
    const float* __restrict__ slots_mu,
    const float* __restrict__ lsg, const float* __restrict__ lsb,
    const short* __restrict__ wq_b,
    float* __restrict__ slbuf, short* __restrict__ slbG, short* __restrict__ qb) {
  __shared__ float sl[8][256];
  __shared__ float mus[8], rss[8];
  __shared__ __align__(16) short slnb[8 * SP];
  int b = blockIdx.x, t = threadIdx.x;
  int wave = t >> 6, lane = t & 63, quad = lane >> 4, lid = lane & 15;
  int arow = (lid & 7) * SP, kof0 = quad << 3;
  for (int idx = t; idx < 2048; idx += 256) {
    float v = slots_mu[idx];
    sl[idx >> 8][idx & 255] = v;
    slbuf[(b << 11) + idx] = v;
    slbG[(b << 11) + idx] = f2bf(v);
  }
  __syncthreads();
  {
    int s0 = (wave << 1) + (lane >> 5);
    int l32 = lane & 31;
    float a0 = 0.f, a1 = 0.f;
    #pragma unroll
    for (int j = 0; j < 8; j++) { float v = sl[s0][l32 + (j << 5)]; a0 += v; a1 += v * v; }
    #pragma unroll
    for (int m = 1; m < 32; m <<= 1) { a0 += __shfl_xor(a0, m); a1 += __shfl_xor(a1, m); }
    if (l32 == 0) {
      float mn = a0 * (1.f / 256.f);
      float var = a1 * (1.f / 256.f) - mn * mn;
      mus[s0] = mn; rss[s0] = rsqrtf(var + EPSV);
    }
  }
  __syncthreads();
  for (int idx = t; idx < 2048; idx += 256) {
    int s = idx >> 8, c = idx & 255;
    slnb[s * SP + c] = f2bf((sl[s][c] - mus[s]) * rss[s] * lsg[c] + lsb[c]);
  }
  __syncthreads();
  #pragma unroll
  for (int nt = 0; nt < 4; nt++) {
    int d = (wave << 6) + (nt << 4) + lid;
    f32x4 qa = 0.f;
    #pragma unroll
    for (int ks = 0; ks < 8; ks++) {
      bf16x8 a = *(const bf16x8*)&slnb[arow + (ks << 5) + kof0];
      bf16x8 bb = *(const bf16x8*)(wq_b + (size_t)d * 256 + (ks << 5) + kof0);
      qa = __builtin_amdgcn_mfma_f32_16x16x32_bf16(a, bb, qa, 0, 0, 0);
    }
    #pragma unroll
    for (int r = 0; r < 4; r++) {
      int s = (quad << 2) + r;
      if (s < 8) qb[(b << 11) + (s << 8) + d] = f2bf(qa[r]);
    }
  }
}

// ---------------- K4: heavy — logits + softmax + partial updates ------------
// grid (16 chunks, 64 b), block 256. chunk = 64 pixels.
__global__ __launch_bounds__(256) void attn_heavy(
    const short* __restrict__ kbuf, const short* __restrict__ vT,
    const short* __restrict__ qb,
    short* __restrict__ partials, float* __restrict__ out_attn, int write_attn) {
  __shared__ __align__(16) short attT[8 * AP];
  int chunk = blockIdx.x, b = blockIdx.y;
  int t = threadIdx.x, wave = t >> 6, lane = t & 63, quad = lane >> 4, lid = lane & 15;
  int kof0 = quad << 3;
  bf16x8 qf[8];
  const short* qpb = qb + ((size_t)b << 11) + (lid & 7) * 256 + kof0;
  #pragma unroll
  for (int ks = 0; ks < 8; ks++) qf[ks] = *(const bf16x8*)(qpb + (ks << 5));
  {
    int p0l = wave << 4;
    const short* kb = kbuf + ((size_t)((b << 10) + (chunk << 6) + p0l + lid)) * 256 + kof0;
    f32x4 la = 0.f;
    #pragma unroll
    for (int ks = 0; ks < 8; ks++) {
      bf16x8 a = *(const bf16x8*)(kb + (ks << 5));
      la = __builtin_amdgcn_mfma_f32_16x16x32_bf16(a, qf[ks], la, 0, 0, 0);
    }
    #pragma unroll
    for (int r = 0; r < 4; r++) {
      float lg = la[r] * 0.0625f;
      float mx = lg;
      #pragma unroll
      for (int m = 1; m < 16; m <<= 1) mx = fmaxf(mx, __shfl_xor(mx, m));
      float e = __expf(lg - mx);
      float sm = e;
      #pragma unroll
      for (int m = 1; m < 16; m <<= 1) sm += __shfl_xor(sm, m);
      float at = (e + e) / sm;
      if (lid < 8) {
        int pl = p0l + (quad << 2) + r;
        attT[lid * AP + pl] = f2bf(at);
        if (write_attn) {
          int p = (chunk << 6) + pl;
          out_attn[((size_t)b << 13) + (p << 3) + lid] = at;
        }
      }
    }
  }
  __syncthreads();
  #pragma unroll
  for (int nt = 0; nt < 4; nt++) {
    int d0 = (wave << 6) + (nt << 4);
    f32x4 ua = 0.f;
    #pragma unroll
    for (int ks = 0; ks < 2; ks++) {
      bf16x8 a = *(const bf16x8*)&attT[(lid & 7) * AP + (ks << 5) + kof0];
      bf16x8 bb = *(const bf16x8*)(vT + (size_t)b * 262144 + (size_t)(d0 + lid) * 1024
                                   + (chunk << 6) + (ks << 5) + kof0);
      ua = __builtin_amdgcn_mfma_f32_16x16x32_bf16(a, bb, ua, 0, 0, 0);
    }
    #pragma unroll
    for (int r = 0; r < 4; r++) {
      int s = (quad << 2) + r;
      if (s < 8)
        partials[(((size_t)(b << 4) + chunk) << 11) + (s << 8) + d0 + lid] = f2bf(ua[r]);
    }
  }
}

// ---------------- K5: reduce partials + GRU + MLP + (LN_s + q next) ---------
__global__ __launch_bounds__(256) void slot_reduce(
    const short* __restrict__ partials,
    float* __restrict__ slbuf, short* __restrict__ slbG, short* __restrict__ qb,
    const short* __restrict__ wih_b, const short* __restrict__ whh_b,
    const float* __restrict__ bih, const float* __restrict__ bhh,
    const float* __restrict__ lmg, const float* __restrict__ lmb,
    const short* __restrict__ w1_b, const float* __restrict__ b1,
    const short* __restrict__ w2_b, const float* __restrict__ b2,
    const float* __restrict__ lsg, const float* __restrict__ lsb,
    const short* __restrict__ wq_b,
    float* __restrict__ out, int last) {
  __shared__ float sl[8][256];
  __shared__ float mus[8], rss[8];
  __shared__ __align__(16) short updb[8 * SP], slb_l[8 * SP], lnmb[8 * SP],
                                  hmb[8 * SP], slnb[8 * SP];
  int b = blockIdx.x, t = threadIdx.x;
  int wave = t >> 6, lane = t & 63, quad = lane >> 4, lid = lane & 15;
  int arow = (lid & 7) * SP, kof0 = quad << 3;
  for (int idx = t; idx < 2048; idx += 256) {
    float sum = 0.f;
    #pragma unroll
    for (int c = 0; c < 16; c++) sum += b2f(partials[(((size_t)(b << 4) + c) << 11) + idx]);
    int s = idx >> 8, dd = idx & 255;
    updb[s * SP + dd] = f2bf(sum);
    sl[s][dd] = slbuf[(b << 11) + idx];
    slb_l[s * SP + dd] = slbG[(b << 11) + idx];
  }
  __syncthreads();
  #pragma unroll
  for (int nt = 0; nt < 4; nt++) {
    int d = (wave << 6) + (nt << 4) + lid;
    f32x4 gi[3], gh[3];
    #pragma unroll
    for (int g = 0; g < 3; g++) { gi[g] = 0.f; gh[g] = 0.f; }
    #pragma unroll
    for (int ks = 0; ks < 8; ks++) {
      bf16x8 au  = *(const bf16x8*)&updb [arow + (ks << 5) + kof0];
      bf16x8 as2 = *(const bf16x8*)&slb_l[arow + (ks << 5) + kof0];
      #pragma unroll
      for (int g = 0; g < 3; g++) {
        bf16x8 bi = *(const bf16x8*)(wih_b + (size_t)((g << 8) + d) * 256 + (ks << 5) + kof0);
        bf16x8 bh = *(const bf16x8*)(whh_b + (size_t)((g << 8) + d) * 256 + (ks << 5) + kof0);
        gi[g] = __builtin_amdgcn_mfma_f32_16x16x32_bf16(au,  bi, gi[g], 0, 0, 0);
        gh[g] = __builtin_amdgcn_mfma_f32_16x16x32_bf16(as2, bh, gh[g], 0, 0, 0);
      }
    }
    float bi0 = bih[d], bi1 = bih[256 + d], bi2 = bih[512 + d];
    float bh0 = bhh[d], bh1 = bhh[256 + d], bh2 = bhh[512 + d];
    #pragma unroll
    for (int r = 0; r < 4; r++) {
      int s = (quad << 2) + r;
      if (s < 8) {
        float rg = 1.f / (1.f + __expf(-(gi[0][r] + bi0 + gh[0][r] + bh0)));
        float zg = 1.f / (1.f + __expf(-(gi[1][r] + bi1 + gh[1][r] + bh1)));
        float ng = tanhf(gi[2][r] + bi2 + rg * (gh[2][r] + bh2));
        sl[s][d] = (1.f - zg) * ng + zg * sl[s][d];
      }
    }
  }
  __syncthreads();
  {
    int s0 = (wave << 1) + (lane >> 5);
    int l32 = lane & 31;
    float a0 = 0.f, a1 = 0.f;
    #pragma unroll
    for (int j = 0; j < 8; j++) { float v = sl[s0][l32 + (j << 5)]; a0 += v; a1 += v * v; }
    #pragma unroll
    for (int m = 1; m < 32; m <<= 1) { a0 += __shfl_xor(a0, m); a1 += __shfl_xor(a1, m); }
    if (l32 == 0) {
      float mn = a0 * (1.f / 256.f);
      float var = a1 * (1.f / 256.f) - mn * mn;
      mus[s0] = mn; rss[s0] = rsqrtf(var + EPSV);
    }
  }
  __syncthreads();
  for (int idx = t; idx < 2048; idx += 256) {
    int s = idx >> 8, c = idx & 255;
    lnmb[s * SP + c] = f2bf((sl[s][c] - mus[s]) * rss[s] * lmg[c] + lmb[c]);
  }
  __syncthreads();
  #pragma unroll
  for (int nt = 0; nt < 4; nt++) {
    int d = (wave << 6) + (nt << 4) + lid;
    f32x4 ha = 0.f;
    #pragma unroll
    for (int ks = 0; ks < 8; ks++) {
      bf16x8 a = *(const bf16x8*)&lnmb[arow + (ks << 5) + kof0];
      bf16x8 bb = *(const bf16x8*)(w1_b + (size_t)d * 256 + (ks << 5) + kof0);
      ha = __builtin_amdgcn_mfma_f32_16x16x32_bf16(a, bb, ha, 0, 0, 0);
    }
    float bb1 = b1[d];
    #pragma unroll
    for (int r = 0; r < 4; r++) {
      int s = (quad << 2) + r;
      if (s < 8) hmb[s * SP + d] = f2bf(fmaxf(ha[r] + bb1, 0.f));
    }
  }
  __syncthreads();
  #pragma unroll
  for (int nt = 0; nt < 4; nt++) {
    int d = (wave << 6) + (nt << 4) + lid;
    f32x4 oa = 0.f;
    #pragma unroll
    for (int ks = 0; ks < 8; ks++) {
      bf16x8 a = *(const bf16x8*)&hmb[arow + (ks << 5) + kof0];
      bf16x8 bb = *(const bf16x8*)(w2_b + (size_t)d * 256 + (ks << 5) + kof0);
      oa = __builtin_amdgcn_mfma_f32_16x16x32_bf16(a, bb, oa, 0, 0, 0);
    }
    float bb2 = b2[d];
    #pragma unroll
    for (int r = 0; r < 4; r++) {
      int s = (quad << 2) + r;
      if (s < 8) sl[s][d] = sl[s][d] + oa[r] + bb2;
    }
  }
  __syncthreads();
  if (last) {
    for (int idx = t; idx < 2048; idx += 256)
      out[(b << 11) + idx] = sl[idx >> 8][idx & 255];
    return;
  }
  for (int idx = t; idx < 2048; idx += 256) {
    float v = sl[idx >> 8][idx & 255];
    slbuf[(b << 11) + idx] = v;
    slbG[(b << 11) + idx] = f2bf(v);
  }
  {
    int s0 = (wave << 1) + (lane >> 5);
    int l32 = lane & 31;
    float a0 = 0.f, a1 = 0.f;
    #pragma unroll
    for (int j = 0; j < 8; j++) { float v = sl[s0][l32 + (j << 5)]; a0 += v; a1 += v * v; }
    #pragma unroll
    for (int m = 1; m < 32; m <<= 1) { a0 += __shfl_xor(a0, m); a1 += __shfl_xor(a1, m); }
    if (l32 == 0) {
      float mn = a0 * (1.f / 256.f);
      float var = a1 * (1.f / 256.f) - mn * mn;
      mus[s0] = mn; rss[s0] = rsqrtf(var + EPSV);
    }
  }
  __syncthreads();
  for (int idx = t; idx < 2048; idx += 256) {
    int s = idx >> 8, c = idx & 255;
    slnb[s * SP + c] = f2bf((sl[s][c] - mus[s]) * rss[s] * lsg[c] + lsb[c]);
  }
  __syncthreads();
  #pragma unroll
  for (int nt = 0; nt < 4; nt++) {
    int d = (wave << 6) + (nt << 4) + lid;
    f32x4 qa = 0.f;
    #pragma unroll
    for (int ks = 0; ks < 8; ks++) {
      bf16x8 a = *(const bf16x8*)&slnb[arow + (ks << 5) + kof0];
      bf16x8 bb = *(const bf16x8*)(wq_b + (size_t)d * 256 + (ks << 5) + kof0);
      qa = __builtin_amdgcn_mfma_f32_16x16x32_bf16(a, bb, qa, 0, 0, 0);
    }
    #pragma unroll
    for (int r = 0; r < 4; r++) {
      int s = (quad << 2) + r;
      if (s < 8) qb[(b << 11) + (s << 8) + d] = f2bf(qa[r]);
    }
  }
}

extern "C" void kernel_launch(void* const* d_in, const int* in_sizes, int n_in,
                              void* d_out, int out_size, void* d_ws, size_t ws_size,
                              hipStream_t stream) {
  const float* x        = (const float*)d_in[0];
  const float* slots_mu = (const float*)d_in[1];
  const float* ln_in_g  = (const float*)d_in[2];
  const float* ln_in_b  = (const float*)d_in[3];
  const float* wk       = (const float*)d_in[4];
  const float* wv       = (const float*)d_in[5];
  const float* ln_s_g   = (const float*)d_in[6];
  const float* ln_s_b   = (const float*)d_in[7];
  const float* wq       = (const float*)d_in[8];
  const float* wih      = (const float*)d_in[9];
  const float* whh      = (const float*)d_in[10];
  const float* bih      = (const float*)d_in[11];
  const float* bhh      = (const float*)d_in[12];
  const float* lmg      = (const float*)d_in[13];
  const float* lmb      = (const float*)d_in[14];
  const float* w1       = (const float*)d_in[15];
  const float* b1       = (const float*)d_in[16];
  const float* w2       = (const float*)d_in[17];
  const float* b2       = (const float*)d_in[18];
  float* out = (float*)d_out;
  float* out_attn = out + 131072;

  char* ws = (char*)d_ws;
  short* kbuf   = (short*)(ws);                  // 33,554,432
  short* vT     = (short*)(ws + 33554432);       // 33,554,432
  short* wkv_b  = (short*)(ws + 67108864);       //    262,144
  short* wq_b   = (short*)(ws + 67371008);       //    131,072
  short* wih_b  = (short*)(ws + 67502080);       //    393,216
  short* whh_b  = (short*)(ws + 67895296);       //    393,216
  short* w1_b   = (short*)(ws + 68288512);       //    131,072
  short* w2_b   = (short*)(ws + 68419584);       //    131,072
  float* slbuf  = (float*)(ws + 68550656);       //    524,288
  short* slbG   = (short*)(ws + 69074944);       //    262,144
  short* qb     = (short*)(ws + 69337088);       //    262,144
  short* parts  = (short*)(ws + 69599232);       //  4,194,304
  float* kvA    = (float*)(ws + 73793536);       //      2,048
  float* kvB    = (float*)(ws + 73795584);       //      2,048 -> 73,797,632

  wcvt<<<2304, 256, 0, stream>>>(wq, wih, whh, w1, w2,
                                 wq_b, wih_b, whh_b, w1_b, w2_b);
  wfold<<<512, 256, 0, stream>>>(wk, wv, ln_in_g, ln_in_b, wkv_b, kvA, kvB);
  kv_gemm<<<512, 256, 0, stream>>>(x, wkv_b, kvA, kvB, kbuf, vT);
  slot_init<<<64, 256, 0, stream>>>(slots_mu, ln_s_g, ln_s_b, wq_b, slbuf, slbG, qb);
  for (int it = 0; it < 3; it++) {
    attn_heavy<<<dim3(16, 64), 256, 0, stream>>>(kbuf, vT, qb, parts, out_attn,
                                                 (it == 2) ? 1 : 0);
    slot_reduce<<<64, 256, 0, stream>>>(parts, slbuf, slbG, qb,
                                        wih_b, whh_b, bih, bhh, lmg, lmb,
                                        w1_b, b1, w2_b, b2, ln_s_g, ln_s_b, wq_b,
                                        out, (it == 2) ? 1 : 0);
  }
}